// Round 7
// baseline (464.042 us; speedup 1.0000x reference)
//
#include <hip/hip_runtime.h>

typedef _Float16 h16;
typedef _Float16 h16x2 __attribute__((ext_vector_type(2)));
typedef _Float16 h16x4 __attribute__((ext_vector_type(4)));
typedef _Float16 h16x8 __attribute__((ext_vector_type(8)));
typedef float f32x4 __attribute__((ext_vector_type(4)));

// ---- problem constants ----
#define N_IMG 512      // B*C = 8*64
#define C_CH  64
#define H_IN  512
#define W_IN  512
#define NC    259      // subband extent: (512+8-1)//2
#define PIT   260      // f32 LDS pitch (k_fwd)
#define PITH  264      // fp16 subband row pitch (rows 16B-aligned)
#define S_IMGH ((size_t)NC * PITH)
#define NSB    ((size_t)N_IMG * S_IMGH)
#define GPIT  264
#define NSTRIP 33

constexpr float DLO[8] = {
  -0.010597401784997278f,  0.032883011666982945f,  0.030841381835986965f, -0.18703481171888114f,
  -0.02798376941698385f,   0.6308807679295904f,    0.7148465705525415f,    0.23037781330885523f};
constexpr float DHI[8] = {
  -0.23037781330885523f,   0.7148465705525415f,   -0.6308807679295904f,   -0.02798376941698385f,
   0.18703481171888114f,   0.030841381835986965f, -0.032883011666982945f, -0.010597401784997278f};
constexpr float RLO[8] = {
   0.23037781330885523f,   0.7148465705525415f,    0.6308807679295904f,   -0.02798376941698385f,
  -0.18703481171888114f,   0.030841381835986965f,  0.032883011666982945f, -0.010597401784997278f};
constexpr float RHI[8] = {
  -0.010597401784997278f, -0.032883011666982945f,  0.030841381835986965f,  0.18703481171888114f,
  -0.02798376941698385f,  -0.6308807679295904f,    0.7148465705525415f,   -0.23037781330885523f};

// =====================================================================
// Kernel 1: row DWT + column DWT -> LH, HL (fp16) only, plus fused gate
// statistics. 1-D grid with XCD-chunk swizzle.
// =====================================================================
__global__ __launch_bounds__(512) void k_fwd(const float* __restrict__ x,
                                             h16* __restrict__ wsh,
                                             float* __restrict__ stat) {
  __shared__ float sa[22 * PIT];
  __shared__ float sd[22 * PIT];
  // bijective XCD swizzle: nwg = 16896 = 8 * 2112
  const int p = blockIdx.x;
  const int w = (p & 7) * 2112 + (p >> 3);
  const int bc = w / NSTRIP;
  const int bx = w - bc * NSTRIP;
  const int h0 = bx * 8;
  const int hcount = min(8, NC - h0);
  const int nrows = 2 * hcount + 6;
  const int tid = threadIdx.x;
  const int wave = tid >> 6, lane = tid & 63;
  const float* xim = x + (size_t)bc * (H_IN * (size_t)W_IN);

  // Phase A: row DWT into LDS; boundaries from registers (no scalar loads)
  for (int j = wave; j < nrows; j += 8) {
    int r = 2 * h0 - 6 + j;
    r = r < 0 ? -r - 1 : (r >= H_IN ? 2 * H_IN - 1 - r : r);
    const float* xrow = xim + (size_t)r * W_IN;
    float* saj = sa + j * PIT;
    float* sdj = sd + j * PIT;
    const int base = lane ? 8 * lane - 8 : 0;
    const float4 q0 = *(const float4*)(xrow + base);
    const float4 q1 = *(const float4*)(xrow + base + 4);
    const float4 q2 = *(const float4*)(xrow + base + 8);
    const float4 q3 = *(const float4*)(xrow + base + 12);
    const float v[16] = {q0.x, q0.y, q0.z, q0.w, q1.x, q1.y, q1.z, q1.w,
                         q2.x, q2.y, q2.z, q2.w, q3.x, q3.y, q3.z, q3.w};
    float A[4], D[4];
    if (lane == 0) {
#pragma unroll
      for (int i = 0; i < 4; ++i) {
        float a = 0.f, d = 0.f;
#pragma unroll
        for (int m = 0; m < 8; ++m) {
          int pp = 2 * i + 1 - m; pp = pp < 0 ? -pp - 1 : pp;
          const float t = v[pp];
          a += DLO[m] * t; d += DHI[m] * t;
        }
        A[i] = a; D[i] = d;
      }
      *(float4*)(saj) = {A[0], A[1], A[2], A[3]};
      *(float4*)(sdj) = {D[0], D[1], D[2], D[3]};
    } else {
#pragma unroll
      for (int k = 0; k < 4; ++k) {
        float a = 0.f, d = 0.f;
#pragma unroll
        for (int m = 0; m < 8; ++m) {
          const float t = v[2 * k + 9 - m];
          a += DLO[m] * t; d += DHI[m] * t;
        }
        A[k] = a; D[k] = d;
      }
      *(float4*)(saj + 4 * lane) = {A[0], A[1], A[2], A[3]};
      *(float4*)(sdj + 4 * lane) = {D[0], D[1], D[2], D[3]};
      if (lane == 63) {
#pragma unroll
        for (int i = 256; i < 259; ++i) {
          float a = 0.f, d = 0.f;
#pragma unroll
          for (int m = 0; m < 8; ++m) {
            int pp = 2 * i + 1 - m; pp = pp >= 512 ? 1023 - pp : pp;
            const float t = v[pp - 496];
            a += DLO[m] * t; d += DHI[m] * t;
          }
          saj[i] = a; sdj[i] = d;
        }
      }
    }
  }
  __syncthreads();

  // Phase B: column DWT -> LH (DHI over A) and HL (DLO over D)
  h16* __restrict__ LHp = wsh;
  h16* __restrict__ HLp = wsh + NSB;
  const size_t obase = (size_t)bc * S_IMGH;
  const int ntask = hcount * 65;
  float rlh[2][4], rhl[2][4];
#pragma unroll
  for (int slot = 0; slot < 2; ++slot) {
    const int task = tid + slot * 512;
    if (task < ntask) {
      const int dh = task / 65, pq = task - dh * 65;
      const int i0 = 4 * pq;
      float lh[4] = {0, 0, 0, 0}, hl[4] = {0, 0, 0, 0};
#pragma unroll
      for (int m = 0; m < 8; ++m) {
        const int j = 2 * dh + 7 - m;
        const float4 av = *(const float4*)(sa + j * PIT + i0);
        const float4 dv = *(const float4*)(sd + j * PIT + i0);
        lh[0] += DHI[m] * av.x; lh[1] += DHI[m] * av.y; lh[2] += DHI[m] * av.z; lh[3] += DHI[m] * av.w;
        hl[0] += DLO[m] * dv.x; hl[1] += DLO[m] * dv.y; hl[2] += DLO[m] * dv.z; hl[3] += DLO[m] * dv.w;
      }
      if (i0 == 256) { lh[3] = 0.f; hl[3] = 0.f; }
      const size_t ob = obase + (size_t)(h0 + dh) * PITH + i0;
      h16x4 o;
      o[0] = (h16)lh[0]; o[1] = (h16)lh[1]; o[2] = (h16)lh[2]; o[3] = (h16)lh[3];
      *(h16x4*)(LHp + ob) = o;
      o[0] = (h16)hl[0]; o[1] = (h16)hl[1]; o[2] = (h16)hl[2]; o[3] = (h16)hl[3];
      *(h16x4*)(HLp + ob) = o;
#pragma unroll
      for (int k = 0; k < 4; ++k) { rlh[slot][k] = lh[k]; rhl[slot][k] = hl[k]; }
    }
  }
  __syncthreads();

  // Phase C: gate stats. Reuse sa region as scratch.
  float* scol = sa;
  float* prmx = sa + 8 * 264;
  float* prsm = prmx + 520;
#pragma unroll
  for (int slot = 0; slot < 2; ++slot) {
    const int task = tid + slot * 512;
    if (task < ntask) {
      const int dh = task / 65, pq = task - dh * 65;
      *(float4*)(scol + dh * 264 + 4 * pq) = {rhl[slot][0], rhl[slot][1], rhl[slot][2], rhl[slot][3]};
      const float m01 = fmaxf(rlh[slot][0], rlh[slot][1]);
      const float m23 = (pq == 64) ? rlh[slot][2] : fmaxf(rlh[slot][2], rlh[slot][3]);
      prmx[task] = fmaxf(m01, m23);
      prsm[task] = rlh[slot][0] + rlh[slot][1] + rlh[slot][2] + rlh[slot][3];
    }
  }
  __syncthreads();
  float* rsM = stat;
  float* rsS = stat + (size_t)N_IMG * 264;
  float* cpM = rsS + (size_t)N_IMG * 264;
  float* cpS = cpM + (size_t)N_IMG * NSTRIP * 264;
  if (wave < hcount) {
    float m = prmx[wave * 65 + lane], s = prsm[wave * 65 + lane];
    if (lane == 0) { m = fmaxf(m, prmx[wave * 65 + 64]); s += prsm[wave * 65 + 64]; }
#pragma unroll
    for (int off = 32; off; off >>= 1) {
      m = fmaxf(m, __shfl_xor(m, off)); s += __shfl_xor(s, off);
    }
    if (lane == 0) {
      rsM[bc * 264 + h0 + wave] = m;
      rsS[bc * 264 + h0 + wave] = s;
    }
  }
  if (tid < 264) {
    float m = -3.4e38f, s = 0.f;
    for (int dh = 0; dh < hcount; ++dh) {
      const float vv = scol[dh * 264 + tid]; m = fmaxf(m, vv); s += vv;
    }
    const size_t cb = ((size_t)bc * NSTRIP + bx) * 264 + tid;
    cpM[cb] = m; cpS[cb] = s;
  }
}

// =====================================================================
// Kernel 2: finish gates from stats only. Writes (sigmoid(y) - 1).
// =====================================================================
__global__ __launch_bounds__(256) void k_gate(
    const float* __restrict__ stat, float* __restrict__ gout,
    const float* lc1w, const float* lc1b, const float* lc2w,
    const float* lg, const float* lb, const float* lm, const float* lv,
    const float* hc1w, const float* hc1b, const float* hc2w,
    const float* hg, const float* hb, const float* hm, const float* hv) {
  __shared__ float cmx[264], csm[264], y0a[264], y0b[264];
  const int bc = blockIdx.x;
  const int tid = threadIdx.x;
  const float* rsM = stat;
  const float* rsS = stat + (size_t)N_IMG * 264;
  const float* cpM = rsS + (size_t)N_IMG * 264;
  const float* cpS = cpM + (size_t)N_IMG * NSTRIP * 264;

  for (int col = tid; col < 264; col += 256) {
    float m = -3.4e38f, s = 0.f;
    for (int st = 0; st < NSTRIP; ++st) {
      const size_t cb = ((size_t)bc * NSTRIP + st) * 264 + col;
      m = fmaxf(m, cpM[cb]); s += cpS[cb];
    }
    cmx[col] = m; csm[col] = s;
  }
  __syncthreads();
  const float lw0 = lc1w[0], lw1 = lc1w[1], lbb0 = lc1b[0];
  const float hw0 = hc1w[0], hw1 = hc1w[1], hbb0 = hc1b[0];
  for (int idx = tid; idx < NC; idx += 256) {
    y0a[idx] = lw0 * rsM[bc * 264 + idx] + lw1 * (rsS[bc * 264 + idx] * (1.f / NC)) + lbb0;
    y0b[idx] = hw0 * cmx[idx] + hw1 * (csm[idx] * (1.f / NC)) + hbb0;
  }
  __syncthreads();
  const int c = bc & (C_CH - 1);
  const float lk0 = lc2w[c * 3], lk1 = lc2w[c * 3 + 1], lk2 = lc2w[c * 3 + 2];
  const float hk0 = hc2w[c * 3], hk1 = hc2w[c * 3 + 1], hk2 = hc2w[c * 3 + 2];
  const float lsc = rsqrtf(lv[c] + 1e-5f) * lg[c], lmu = lm[c], lbe = lb[c];
  const float hsc = rsqrtf(hv[c] + 1e-5f) * hg[c], hmu = hm[c], hbe = hb[c];
  for (int idx = tid; idx < NC; idx += 256) {
    float a = idx > 0 ? y0a[idx - 1] : 0.f;
    float b = y0a[idx];
    float d = idx < NC - 1 ? y0a[idx + 1] : 0.f;
    float y = lk0 * a + lk1 * b + lk2 * d;
    y = (y - lmu) * lsc + lbe;
    gout[(size_t)bc * GPIT + idx] = 1.f / (1.f + expf(-y)) - 1.f;

    a = idx > 0 ? y0b[idx - 1] : 0.f;
    b = y0b[idx];
    d = idx < NC - 1 ? y0b[idx + 1] : 0.f;
    y = hk0 * a + hk1 * b + hk2 * d;
    y = (y - hmu) * hsc + hbe;
    gout[(size_t)N_IMG * GPIT + (size_t)bc * GPIT + idx] = 1.f / (1.f + expf(-y)) - 1.f;
  }
}

// =====================================================================
// Kernel 3: out = 2x + IDWT(0, (g-1)LH, (g'-1)HL, 0).
// 16-row strips; column IDWT reads fp16 subbands DIRECTLY from global
// (L1 serves the per-row reuse) with gates folded; single barrier.
// =====================================================================
__global__ __launch_bounds__(512) void k_inv(const h16* __restrict__ wsh,
                                             const float* __restrict__ gbuf,
                                             const float* __restrict__ x,
                                             float* __restrict__ out) {
  __shared__ float a2[16][PITH], d2[16][PITH];
  // bijective XCD swizzle: nwg = 16384 = 8 * 2048
  const int p = blockIdx.x;
  const int w = (p & 7) * 2048 + (p >> 3);
  const int bc = w >> 5;               // 32 strips of 16 rows per image
  const int t0 = (w & 31) * 16;
  const int u0 = t0 >> 1;              // subband rows u0..u0+10 (<= 258)
  const int tid = threadIdx.x;
  const h16* LHh = wsh       + (size_t)bc * S_IMGH;
  const h16* HLh = wsh + NSB + (size_t)bc * S_IMGH;
  const float* glh = gbuf + (size_t)bc * GPIT;
  const float* ghl = gbuf + (size_t)N_IMG * GPIT + (size_t)bc * GPIT;

  // Phase 1: column IDWT directly from global fp16 subbands.
  // a2[dt][i] = sum_jj RHI*glh[u] * LH[u][i] ; d2 = ghl[i]*sum RLO*HL[u][i]
  for (int task = tid; task < 16 * 132; task += 512) {
    const int dt = task / 132, pq = task - dt * 132;
    const int i = 2 * pq;
    const int par = dt & 1, lj0 = dt >> 1;
    float ax = 0.f, ay = 0.f, dx_ = 0.f, dy_ = 0.f;
#pragma unroll
    for (int jj = 0; jj < 4; ++jj) {
      const int u = u0 + lj0 + 3 - jj;
      const float rhg = (par ? RHI[1 + 2 * jj] : RHI[2 * jj]) * glh[u];
      const float rl = par ? RLO[1 + 2 * jj] : RLO[2 * jj];
      const size_t rb = (size_t)u * PITH + i;
      const h16x2 bv = *(const h16x2*)(LHh + rb);
      const h16x2 cv = *(const h16x2*)(HLh + rb);
      ax += (float)bv[0] * rhg; ay += (float)bv[1] * rhg;
      dx_ += (float)cv[0] * rl; dy_ += (float)cv[1] * rl;
    }
    const float2 gh = *(const float2*)(ghl + i);
    *(float2*)(&a2[dt][i]) = {ax, ay};
    *(float2*)(&d2[dt][i]) = {gh.x * dx_, gh.y * dy_};
  }
  __syncthreads();

  // Phase 2: row IDWT + out = 2x + corr (nontemporal x/out)
  for (int task = tid; task < 16 * 128; task += 512) {
    const int dt = task >> 7, r = task & 127;
    const int q = 2 * r;
    const float a_[5] = {a2[dt][q], a2[dt][q + 1], a2[dt][q + 2], a2[dt][q + 3], a2[dt][q + 4]};
    const float d_[5] = {d2[dt][q], d2[dt][q + 1], d2[dt][q + 2], d2[dt][q + 3], d2[dt][q + 4]};
    float vv[4];
#pragma unroll
    for (int k = 0; k < 4; ++k) {
      float s = 0.f;
      const int base = k >> 1, par = k & 1;
#pragma unroll
      for (int jj = 0; jj < 4; ++jj)
        s += a_[base + 3 - jj] * RLO[par + 2 * jj] + d_[base + 3 - jj] * RHI[par + 2 * jj];
      vv[k] = s;
    }
    const size_t orow = ((size_t)bc * H_IN + (size_t)(t0 + dt)) * W_IN + 4 * r;
    const f32x4 xv = __builtin_nontemporal_load((const f32x4*)(x + orow));
    f32x4 ov;
    ov.x = 2.f * xv.x + vv[0]; ov.y = 2.f * xv.y + vv[1];
    ov.z = 2.f * xv.z + vv[2]; ov.w = 2.f * xv.w + vv[3];
    __builtin_nontemporal_store(ov, (f32x4*)(out + orow));
  }
}

extern "C" void kernel_launch(void* const* d_in, const int* in_sizes, int n_in,
                              void* d_out, int out_size, void* d_ws, size_t ws_size,
                              hipStream_t stream) {
  const float* x = (const float*)d_in[0];
  h16* wsh = (h16*)d_ws;
  float* statf = (float*)(wsh + 2 * NSB);
  float* gbuf = statf + 2 * (size_t)N_IMG * 264 + 2 * (size_t)N_IMG * NSTRIP * 264;
  float* out = (float*)d_out;

  k_fwd<<<dim3(NSTRIP * N_IMG), 512, 0, stream>>>(x, wsh, statf);
  k_gate<<<dim3(N_IMG), 256, 0, stream>>>(
      statf, gbuf,
      (const float*)d_in[1], (const float*)d_in[2], (const float*)d_in[3],
      (const float*)d_in[4], (const float*)d_in[5], (const float*)d_in[6], (const float*)d_in[7],
      (const float*)d_in[8], (const float*)d_in[9], (const float*)d_in[10],
      (const float*)d_in[11], (const float*)d_in[12], (const float*)d_in[13], (const float*)d_in[14]);
  k_inv<<<dim3(32 * N_IMG), 512, 0, stream>>>(wsh, gbuf, x, out);
}

// Round 8
// 405.815 us; speedup vs baseline: 1.1435x; 1.1435x over previous
//
#include <hip/hip_runtime.h>

typedef _Float16 h16;
typedef _Float16 h16x2 __attribute__((ext_vector_type(2)));
typedef _Float16 h16x4 __attribute__((ext_vector_type(4)));
typedef _Float16 h16x8 __attribute__((ext_vector_type(8)));
typedef float f32x4 __attribute__((ext_vector_type(4)));

// ---- problem constants ----
#define N_IMG 512      // B*C = 8*64
#define C_CH  64
#define H_IN  512
#define W_IN  512
#define NC    259      // subband extent: (512+8-1)//2
#define PITH  264      // fp16 subband row pitch (rows 16B-aligned)
#define S_IMGH ((size_t)NC * PITH)
#define NSB    ((size_t)N_IMG * S_IMGH)
#define GPIT  264
#define FSTRIP 17      // k_fwd: 17 strips of 16 subband rows
#define LROWS  38      // max x-rows per strip: 2*16+6

constexpr float DLO[8] = {
  -0.010597401784997278f,  0.032883011666982945f,  0.030841381835986965f, -0.18703481171888114f,
  -0.02798376941698385f,   0.6308807679295904f,    0.7148465705525415f,    0.23037781330885523f};
constexpr float DHI[8] = {
  -0.23037781330885523f,   0.7148465705525415f,   -0.6308807679295904f,   -0.02798376941698385f,
   0.18703481171888114f,   0.030841381835986965f, -0.032883011666982945f, -0.010597401784997278f};
constexpr float RLO[8] = {
   0.23037781330885523f,   0.7148465705525415f,    0.6308807679295904f,   -0.02798376941698385f,
  -0.18703481171888114f,   0.030841381835986965f,  0.032883011666982945f, -0.010597401784997278f};
constexpr float RHI[8] = {
  -0.010597401784997278f, -0.032883011666982945f,  0.030841381835986965f,  0.18703481171888114f,
  -0.02798376941698385f,  -0.6308807679295904f,    0.7148465705525415f,   -0.23037781330885523f};

// =====================================================================
// Kernel 1: row DWT + column DWT -> LH, HL (fp16), fused gate stats.
// 16-subband-row strips (halo 1.19x), fp16 LDS intermediates (40 KB ->
// 4 blocks/CU), XCD-chunk swizzle.
// =====================================================================
__global__ __launch_bounds__(512) void k_fwd(const float* __restrict__ x,
                                             h16* __restrict__ wsh,
                                             float* __restrict__ stat) {
  __shared__ h16 sa16[LROWS * PITH];   // 20064 B
  __shared__ h16 sd16[LROWS * PITH];   // 20064 B
  // bijective XCD swizzle: nwg = 512*17 = 8704 = 8 * 1088
  const int p = blockIdx.x;
  const int w = (p & 7) * 1088 + (p >> 3);
  const int bc = w / FSTRIP;
  const int bx = w - bc * FSTRIP;
  const int h0 = bx * 16;
  const int hcount = min(16, NC - h0);
  const int nrows = 2 * hcount + 6;
  const int tid = threadIdx.x;
  const int wave = tid >> 6, lane = tid & 63;
  const float* xim = x + (size_t)bc * (H_IN * (size_t)W_IN);

  // Phase A: row DWT into fp16 LDS; boundaries from registers
  for (int j = wave; j < nrows; j += 8) {
    int r = 2 * h0 - 6 + j;
    r = r < 0 ? -r - 1 : (r >= H_IN ? 2 * H_IN - 1 - r : r);
    const float* xrow = xim + (size_t)r * W_IN;
    h16* saj = sa16 + j * PITH;
    h16* sdj = sd16 + j * PITH;
    const int base = lane ? 8 * lane - 8 : 0;
    const float4 q0 = *(const float4*)(xrow + base);
    const float4 q1 = *(const float4*)(xrow + base + 4);
    const float4 q2 = *(const float4*)(xrow + base + 8);
    const float4 q3 = *(const float4*)(xrow + base + 12);
    const float v[16] = {q0.x, q0.y, q0.z, q0.w, q1.x, q1.y, q1.z, q1.w,
                         q2.x, q2.y, q2.z, q2.w, q3.x, q3.y, q3.z, q3.w};
    float A[4], D[4];
    if (lane == 0) {
#pragma unroll
      for (int i = 0; i < 4; ++i) {
        float a = 0.f, d = 0.f;
#pragma unroll
        for (int m = 0; m < 8; ++m) {
          int pp = 2 * i + 1 - m; pp = pp < 0 ? -pp - 1 : pp;
          const float t = v[pp];
          a += DLO[m] * t; d += DHI[m] * t;
        }
        A[i] = a; D[i] = d;
      }
      h16x4 oa, od;
#pragma unroll
      for (int k = 0; k < 4; ++k) { oa[k] = (h16)A[k]; od[k] = (h16)D[k]; }
      *(h16x4*)(saj) = oa; *(h16x4*)(sdj) = od;
    } else {
#pragma unroll
      for (int k = 0; k < 4; ++k) {
        float a = 0.f, d = 0.f;
#pragma unroll
        for (int m = 0; m < 8; ++m) {
          const float t = v[2 * k + 9 - m];
          a += DLO[m] * t; d += DHI[m] * t;
        }
        A[k] = a; D[k] = d;
      }
      h16x4 oa, od;
#pragma unroll
      for (int k = 0; k < 4; ++k) { oa[k] = (h16)A[k]; od[k] = (h16)D[k]; }
      *(h16x4*)(saj + 4 * lane) = oa; *(h16x4*)(sdj + 4 * lane) = od;
      if (lane == 63) {
#pragma unroll
        for (int i = 256; i < 259; ++i) {
          float a = 0.f, d = 0.f;
#pragma unroll
          for (int m = 0; m < 8; ++m) {
            int pp = 2 * i + 1 - m; pp = pp >= 512 ? 1023 - pp : pp;
            const float t = v[pp - 496];
            a += DLO[m] * t; d += DHI[m] * t;
          }
          saj[i] = (h16)a; sdj[i] = (h16)d;
        }
      }
    }
  }
  __syncthreads();

  // Phase B: column DWT -> LH (DHI over A) and HL (DLO over D)
  h16* __restrict__ LHp = wsh;
  h16* __restrict__ HLp = wsh + NSB;
  const size_t obase = (size_t)bc * S_IMGH;
  const int ntask = hcount * 65;            // <= 1040
  float rlh[3][4], rhl[3][4];
#pragma unroll
  for (int slot = 0; slot < 3; ++slot) {
    const int task = tid + slot * 512;
    if (task < ntask) {
      const int dh = task / 65, pq = task - dh * 65;
      const int i0 = 4 * pq;
      float lh[4] = {0, 0, 0, 0}, hl[4] = {0, 0, 0, 0};
#pragma unroll
      for (int m = 0; m < 8; ++m) {
        const int j = 2 * dh + 7 - m;
        const h16x4 av = *(const h16x4*)(sa16 + j * PITH + i0);
        const h16x4 dv = *(const h16x4*)(sd16 + j * PITH + i0);
        lh[0] += DHI[m] * (float)av[0]; lh[1] += DHI[m] * (float)av[1];
        lh[2] += DHI[m] * (float)av[2]; lh[3] += DHI[m] * (float)av[3];
        hl[0] += DLO[m] * (float)dv[0]; hl[1] += DLO[m] * (float)dv[1];
        hl[2] += DLO[m] * (float)dv[2]; hl[3] += DLO[m] * (float)dv[3];
      }
      if (i0 == 256) { lh[3] = 0.f; hl[3] = 0.f; }
      const size_t ob = obase + (size_t)(h0 + dh) * PITH + i0;
      h16x4 o;
      o[0] = (h16)lh[0]; o[1] = (h16)lh[1]; o[2] = (h16)lh[2]; o[3] = (h16)lh[3];
      *(h16x4*)(LHp + ob) = o;
      o[0] = (h16)hl[0]; o[1] = (h16)hl[1]; o[2] = (h16)hl[2]; o[3] = (h16)hl[3];
      *(h16x4*)(HLp + ob) = o;
#pragma unroll
      for (int k = 0; k < 4; ++k) { rlh[slot][k] = lh[k]; rhl[slot][k] = hl[k]; }
    }
  }
  __syncthreads();

  // Phase C: gate stats; reuse LDS as f32 scratch
  float* scol = (float*)sa16;          // [16][264] = 16896 B <= 20064
  float* prmx = (float*)sd16;          // [1056]
  float* prsm = prmx + 1056;           // [1040] -> total 8384 B <= 20064
#pragma unroll
  for (int slot = 0; slot < 3; ++slot) {
    const int task = tid + slot * 512;
    if (task < ntask) {
      const int dh = task / 65, pq = task - dh * 65;
      *(float4*)(scol + dh * 264 + 4 * pq) = {rhl[slot][0], rhl[slot][1], rhl[slot][2], rhl[slot][3]};
      const float m01 = fmaxf(rlh[slot][0], rlh[slot][1]);
      const float m23 = (pq == 64) ? rlh[slot][2] : fmaxf(rlh[slot][2], rlh[slot][3]);
      prmx[task] = fmaxf(m01, m23);
      prsm[task] = rlh[slot][0] + rlh[slot][1] + rlh[slot][2] + rlh[slot][3];
    }
  }
  __syncthreads();
  float* rsM = stat;
  float* rsS = stat + (size_t)N_IMG * 264;
  float* cpM = rsS + (size_t)N_IMG * 264;
  float* cpS = cpM + (size_t)N_IMG * FSTRIP * 264;
  for (int hh = wave; hh < hcount; hh += 8) {
    float m = prmx[hh * 65 + lane], s = prsm[hh * 65 + lane];
    if (lane == 0) { m = fmaxf(m, prmx[hh * 65 + 64]); s += prsm[hh * 65 + 64]; }
#pragma unroll
    for (int off = 32; off; off >>= 1) {
      m = fmaxf(m, __shfl_xor(m, off)); s += __shfl_xor(s, off);
    }
    if (lane == 0) {
      rsM[bc * 264 + h0 + hh] = m;
      rsS[bc * 264 + h0 + hh] = s;
    }
  }
  if (tid < 264) {
    float m = -3.4e38f, s = 0.f;
    for (int dh = 0; dh < hcount; ++dh) {
      const float vv = scol[dh * 264 + tid]; m = fmaxf(m, vv); s += vv;
    }
    const size_t cb = ((size_t)bc * FSTRIP + bx) * 264 + tid;
    cpM[cb] = m; cpS[cb] = s;
  }
}

// =====================================================================
// Kernel 2: finish gates from stats only. Writes (sigmoid(y) - 1).
// =====================================================================
__global__ __launch_bounds__(256) void k_gate(
    const float* __restrict__ stat, float* __restrict__ gout,
    const float* lc1w, const float* lc1b, const float* lc2w,
    const float* lg, const float* lb, const float* lm, const float* lv,
    const float* hc1w, const float* hc1b, const float* hc2w,
    const float* hg, const float* hb, const float* hm, const float* hv) {
  __shared__ float cmx[264], csm[264], y0a[264], y0b[264];
  const int bc = blockIdx.x;
  const int tid = threadIdx.x;
  const float* rsM = stat;
  const float* rsS = stat + (size_t)N_IMG * 264;
  const float* cpM = rsS + (size_t)N_IMG * 264;
  const float* cpS = cpM + (size_t)N_IMG * FSTRIP * 264;

  for (int col = tid; col < 264; col += 256) {
    float m = -3.4e38f, s = 0.f;
    for (int st = 0; st < FSTRIP; ++st) {
      const size_t cb = ((size_t)bc * FSTRIP + st) * 264 + col;
      m = fmaxf(m, cpM[cb]); s += cpS[cb];
    }
    cmx[col] = m; csm[col] = s;
  }
  __syncthreads();
  const float lw0 = lc1w[0], lw1 = lc1w[1], lbb0 = lc1b[0];
  const float hw0 = hc1w[0], hw1 = hc1w[1], hbb0 = hc1b[0];
  for (int idx = tid; idx < NC; idx += 256) {
    y0a[idx] = lw0 * rsM[bc * 264 + idx] + lw1 * (rsS[bc * 264 + idx] * (1.f / NC)) + lbb0;
    y0b[idx] = hw0 * cmx[idx] + hw1 * (csm[idx] * (1.f / NC)) + hbb0;
  }
  __syncthreads();
  const int c = bc & (C_CH - 1);
  const float lk0 = lc2w[c * 3], lk1 = lc2w[c * 3 + 1], lk2 = lc2w[c * 3 + 2];
  const float hk0 = hc2w[c * 3], hk1 = hc2w[c * 3 + 1], hk2 = hc2w[c * 3 + 2];
  const float lsc = rsqrtf(lv[c] + 1e-5f) * lg[c], lmu = lm[c], lbe = lb[c];
  const float hsc = rsqrtf(hv[c] + 1e-5f) * hg[c], hmu = hm[c], hbe = hb[c];
  for (int idx = tid; idx < NC; idx += 256) {
    float a = idx > 0 ? y0a[idx - 1] : 0.f;
    float b = y0a[idx];
    float d = idx < NC - 1 ? y0a[idx + 1] : 0.f;
    float y = lk0 * a + lk1 * b + lk2 * d;
    y = (y - lmu) * lsc + lbe;
    gout[(size_t)bc * GPIT + idx] = 1.f / (1.f + expf(-y)) - 1.f;

    a = idx > 0 ? y0b[idx - 1] : 0.f;
    b = y0b[idx];
    d = idx < NC - 1 ? y0b[idx + 1] : 0.f;
    y = hk0 * a + hk1 * b + hk2 * d;
    y = (y - hmu) * hsc + hbe;
    gout[(size_t)N_IMG * GPIT + (size_t)bc * GPIT + idx] = 1.f / (1.f + expf(-y)) - 1.f;
  }
}

// =====================================================================
// Kernel 3 (Round-6 form): out = 2x + IDWT(0, (g-1)LH, (g'-1)HL, 0).
// 8-row strips, LDS staging, folded gates, XCD swizzle, NT x/out.
// =====================================================================
__global__ __launch_bounds__(512) void k_inv(const h16* __restrict__ wsh,
                                             const float* __restrict__ gbuf,
                                             const float* __restrict__ x,
                                             float* __restrict__ out) {
  __shared__ float sB[7][PITH], sC[7][PITH];
  __shared__ float a2[8][PITH], d2[8][PITH];
  __shared__ float sghl[PITH];
  // bijective XCD swizzle: nwg = 32768 = 8 * 4096
  const int p = blockIdx.x;
  const int w = (p & 7) * 4096 + (p >> 3);
  const int bc = w >> 6;
  const int t0 = (w & 63) * 8;
  const int u0 = t0 >> 1;
  const int tid = threadIdx.x;
  const h16* LHh = wsh       + (size_t)bc * S_IMGH;
  const h16* HLh = wsh + NSB + (size_t)bc * S_IMGH;
  const float* glh = gbuf + (size_t)bc * GPIT;
  const float* ghl = gbuf + (size_t)N_IMG * GPIT + (size_t)bc * GPIT;

  if (tid < 66) *(float4*)(sghl + 4 * tid) = *(const float4*)(ghl + 4 * tid);

  // stage 7 rows of LH*(g-1) and raw HL
  for (int q = tid; q < 7 * 33; q += 512) {
    const int j = q / 33, b8 = (q - j * 33) * 8;
    const int u = u0 + j;
    const float gl = glh[u];                    // (g - 1)
    const size_t rb = (size_t)u * PITH + b8;
    const h16x8 Bv = *(const h16x8*)(LHh + rb);
    const h16x8 Cv = *(const h16x8*)(HLh + rb);
    float4 f0 = {(float)Bv[0] * gl, (float)Bv[1] * gl, (float)Bv[2] * gl, (float)Bv[3] * gl};
    float4 f1 = {(float)Bv[4] * gl, (float)Bv[5] * gl, (float)Bv[6] * gl, (float)Bv[7] * gl};
    *(float4*)(&sB[j][b8]) = f0; *(float4*)(&sB[j][b8 + 4]) = f1;
    f0 = {(float)Cv[0], (float)Cv[1], (float)Cv[2], (float)Cv[3]};
    f1 = {(float)Cv[4], (float)Cv[5], (float)Cv[6], (float)Cv[7]};
    *(float4*)(&sC[j][b8]) = f0; *(float4*)(&sC[j][b8 + 4]) = f1;
  }
  __syncthreads();

  // column IDWT halves: a2 = RHI ⊗ sB ; d2 = (g'-1) * (RLO ⊗ sC)
  for (int task = tid; task < 8 * 132; task += 512) {
    const int dt = task / 132, pq = task - dt * 132;
    const int i = 2 * pq;
    const int par = dt & 1, lj0 = dt >> 1;
    float ax = 0.f, ay = 0.f, dx_ = 0.f, dy_ = 0.f;
#pragma unroll
    for (int jj = 0; jj < 4; ++jj) {
      const int lj = lj0 + 3 - jj;
      const float rh = par ? RHI[1 + 2 * jj] : RHI[2 * jj];
      const float rl = par ? RLO[1 + 2 * jj] : RLO[2 * jj];
      const float2 b_ = *(const float2*)(&sB[lj][i]);
      const float2 c_ = *(const float2*)(&sC[lj][i]);
      ax += b_.x * rh; ay += b_.y * rh;
      dx_ += c_.x * rl; dy_ += c_.y * rl;
    }
    *(float2*)(&a2[dt][i]) = {ax, ay};
    *(float2*)(&d2[dt][i]) = {sghl[i] * dx_, sghl[i + 1] * dy_};
  }
  __syncthreads();

  // row IDWT + out = 2x + corr (nontemporal x/out)
  for (int task = tid; task < 8 * 128; task += 512) {
    const int dt = task >> 7, r = task & 127;
    const int q = 2 * r;
    const float a_[5] = {a2[dt][q], a2[dt][q + 1], a2[dt][q + 2], a2[dt][q + 3], a2[dt][q + 4]};
    const float d_[5] = {d2[dt][q], d2[dt][q + 1], d2[dt][q + 2], d2[dt][q + 3], d2[dt][q + 4]};
    float vv[4];
#pragma unroll
    for (int k = 0; k < 4; ++k) {
      float s = 0.f;
      const int base = k >> 1, par = k & 1;
#pragma unroll
      for (int jj = 0; jj < 4; ++jj)
        s += a_[base + 3 - jj] * RLO[par + 2 * jj] + d_[base + 3 - jj] * RHI[par + 2 * jj];
      vv[k] = s;
    }
    const size_t orow = ((size_t)bc * H_IN + (size_t)(t0 + dt)) * W_IN + 4 * r;
    const f32x4 xv = __builtin_nontemporal_load((const f32x4*)(x + orow));
    f32x4 ov;
    ov.x = 2.f * xv.x + vv[0]; ov.y = 2.f * xv.y + vv[1];
    ov.z = 2.f * xv.z + vv[2]; ov.w = 2.f * xv.w + vv[3];
    __builtin_nontemporal_store(ov, (f32x4*)(out + orow));
  }
}

extern "C" void kernel_launch(void* const* d_in, const int* in_sizes, int n_in,
                              void* d_out, int out_size, void* d_ws, size_t ws_size,
                              hipStream_t stream) {
  const float* x = (const float*)d_in[0];
  h16* wsh = (h16*)d_ws;
  float* statf = (float*)(wsh + 2 * NSB);
  // stat layout: rsM[512*264] | rsS | cpM[512*17*264] | cpS | glh | ghl
  float* gbuf = statf + 2 * (size_t)N_IMG * 264 + 2 * (size_t)N_IMG * FSTRIP * 264;
  float* out = (float*)d_out;

  k_fwd<<<dim3(FSTRIP * N_IMG), 512, 0, stream>>>(x, wsh, statf);
  k_gate<<<dim3(N_IMG), 256, 0, stream>>>(
      statf, gbuf,
      (const float*)d_in[1], (const float*)d_in[2], (const float*)d_in[3],
      (const float*)d_in[4], (const float*)d_in[5], (const float*)d_in[6], (const float*)d_in[7],
      (const float*)d_in[8], (const float*)d_in[9], (const float*)d_in[10],
      (const float*)d_in[11], (const float*)d_in[12], (const float*)d_in[13], (const float*)d_in[14]);
  k_inv<<<dim3(64 * N_IMG), 512, 0, stream>>>(wsh, gbuf, x, out);
}

// Round 9
// 371.152 us; speedup vs baseline: 1.2503x; 1.0934x over previous
//
#include <hip/hip_runtime.h>

typedef _Float16 h16;
typedef _Float16 h16x2 __attribute__((ext_vector_type(2)));
typedef _Float16 h16x4 __attribute__((ext_vector_type(4)));
typedef _Float16 h16x8 __attribute__((ext_vector_type(8)));
typedef float f32x4 __attribute__((ext_vector_type(4)));

#if __has_builtin(__builtin_amdgcn_fdot2)
#define FDOT2(a, b, c) __builtin_amdgcn_fdot2((a), (b), (c), false)
#else
static __device__ __forceinline__ float FDOT2(h16x2 a, h16x2 b, float c) {
  return c + (float)a[0] * (float)b[0] + (float)a[1] * (float)b[1];
}
#endif

// ---- problem constants ----
#define N_IMG 512      // B*C = 8*64
#define C_CH  64
#define H_IN  512
#define W_IN  512
#define NC    259      // subband extent
#define PITP  528      // h16 per interleaved row: 264 (LH,HL)/(A,D) pairs
#define S2    ((size_t)NC * PITP)   // h16 per image (interleaved subband pair)
#define GPIT  264
#define FSTRIP 17      // k_fwd: 17 strips of 16 subband rows
#define LROWS  38      // x-rows per strip: 2*16+6

constexpr float DLO[8] = {
  -0.010597401784997278f,  0.032883011666982945f,  0.030841381835986965f, -0.18703481171888114f,
  -0.02798376941698385f,   0.6308807679295904f,    0.7148465705525415f,    0.23037781330885523f};
constexpr float DHI[8] = {
  -0.23037781330885523f,   0.7148465705525415f,   -0.6308807679295904f,   -0.02798376941698385f,
   0.18703481171888114f,   0.030841381835986965f, -0.032883011666982945f, -0.010597401784997278f};
constexpr float RLO[8] = {
   0.23037781330885523f,   0.7148465705525415f,    0.6308807679295904f,   -0.02798376941698385f,
  -0.18703481171888114f,   0.030841381835986965f,  0.032883011666982945f, -0.010597401784997278f};
constexpr float RHI[8] = {
  -0.010597401784997278f, -0.032883011666982945f,  0.030841381835986965f,  0.18703481171888114f,
  -0.02798376941698385f,  -0.6308807679295904f,    0.7148465705525415f,   -0.23037781330885523f};

// =====================================================================
// Kernel 1: row DWT (f32) -> interleaved fp16 (A,D) LDS -> packed-fp16
// column DWT -> interleaved (LH,HL) global + fused gate stats.
// =====================================================================
__global__ __launch_bounds__(512) void k_fwd(const float* __restrict__ x,
                                             h16* __restrict__ wsh,
                                             float* __restrict__ stat) {
  __shared__ h16 sad[LROWS * PITP];          // 40,128 B -> 4 blocks/CU
  // bijective XCD swizzle: nwg = 8704 = 8 * 1088
  const int p = blockIdx.x;
  const int w = (p & 7) * 1088 + (p >> 3);
  const int bc = w / FSTRIP;
  const int bx = w - bc * FSTRIP;
  const int h0 = bx * 16;
  const int hcount = min(16, NC - h0);
  const int nrows = 2 * hcount + 6;
  const int tid = threadIdx.x;
  const int wave = tid >> 6, lane = tid & 63;
  const float* xim = x + (size_t)bc * (H_IN * (size_t)W_IN);

  // Phase A: row DWT (f32 math), store interleaved fp16 pairs
  for (int j = wave; j < nrows; j += 8) {
    int r = 2 * h0 - 6 + j;
    r = r < 0 ? -r - 1 : (r >= H_IN ? 2 * H_IN - 1 - r : r);
    const float* xrow = xim + (size_t)r * W_IN;
    h16* sj = sad + j * PITP;
    const int base = lane ? 8 * lane - 8 : 0;
    const float4 q0 = *(const float4*)(xrow + base);
    const float4 q1 = *(const float4*)(xrow + base + 4);
    const float4 q2 = *(const float4*)(xrow + base + 8);
    const float4 q3 = *(const float4*)(xrow + base + 12);
    const float v[16] = {q0.x, q0.y, q0.z, q0.w, q1.x, q1.y, q1.z, q1.w,
                         q2.x, q2.y, q2.z, q2.w, q3.x, q3.y, q3.z, q3.w};
    if (lane == 0) {
      h16x8 o;
#pragma unroll
      for (int i = 0; i < 4; ++i) {
        float a = 0.f, d = 0.f;
#pragma unroll
        for (int m = 0; m < 8; ++m) {
          int pp = 2 * i + 1 - m; pp = pp < 0 ? -pp - 1 : pp;
          const float t = v[pp];
          a += DLO[m] * t; d += DHI[m] * t;
        }
        o[2 * i] = (h16)a; o[2 * i + 1] = (h16)d;
      }
      *(h16x8*)(sj) = o;
    } else {
      h16x8 o;
#pragma unroll
      for (int k = 0; k < 4; ++k) {
        float a = 0.f, d = 0.f;
#pragma unroll
        for (int m = 0; m < 8; ++m) {
          const float t = v[2 * k + 9 - m];
          a += DLO[m] * t; d += DHI[m] * t;
        }
        o[2 * k] = (h16)a; o[2 * k + 1] = (h16)d;
      }
      *(h16x8*)(sj + 8 * lane) = o;
      if (lane == 63) {
#pragma unroll
        for (int i = 256; i < 259; ++i) {
          float a = 0.f, d = 0.f;
#pragma unroll
          for (int m = 0; m < 8; ++m) {
            int pp = 2 * i + 1 - m; pp = pp >= 512 ? 1023 - pp : pp;
            const float t = v[pp - 496];
            a += DLO[m] * t; d += DHI[m] * t;
          }
          h16x2 o2; o2[0] = (h16)a; o2[1] = (h16)d;
          *(h16x2*)(sj + 2 * i) = o2;
        }
      }
    }
  }
  __syncthreads();

  // Phase B: packed column DWT -> interleaved (LH,HL) global
  const size_t obase = (size_t)bc * S2;
  const int ntask = hcount * 66;             // <= 1056
  float rlh[3][4], rhl[3][4];
#pragma unroll
  for (int slot = 0; slot < 3; ++slot) {
    const int task = tid + slot * 512;
    if (task < ntask) {
      const int dh = task / 66, pq = task - dh * 66;
      h16x2 a0 = {0, 0}, a1 = {0, 0}, a2_ = {0, 0}, a3 = {0, 0};
#pragma unroll
      for (int m = 0; m < 8; ++m) {
        const int j = 2 * dh + 7 - m;
        const h16x8 pr = *(const h16x8*)(sad + j * PITP + 8 * pq);
        const h16x2 cf = {(h16)DHI[m], (h16)DLO[m]};
        const h16x2 p0 = {pr[0], pr[1]}, p1 = {pr[2], pr[3]};
        const h16x2 p2 = {pr[4], pr[5]}, p3 = {pr[6], pr[7]};
        a0 += cf * p0; a1 += cf * p1; a2_ += cf * p2; a3 += cf * p3;
      }
      if (pq == 64) { a3 = (h16x2){0, 0}; }
      if (pq == 65) { a0 = a1 = a2_ = a3 = (h16x2){0, 0}; }
      h16x8 o = {a0[0], a0[1], a1[0], a1[1], a2_[0], a2_[1], a3[0], a3[1]};
      *(h16x8*)(wsh + obase + (size_t)(h0 + dh) * PITP + 8 * pq) = o;
      rlh[slot][0] = (float)a0[0]; rlh[slot][1] = (float)a1[0];
      rlh[slot][2] = (float)a2_[0]; rlh[slot][3] = (float)a3[0];
      rhl[slot][0] = (float)a0[1]; rhl[slot][1] = (float)a1[1];
      rhl[slot][2] = (float)a2_[1]; rhl[slot][3] = (float)a3[1];
    }
  }
  __syncthreads();

  // Phase C: gate stats; reuse sad as f32 scratch
  float* scol = (float*)sad;                 // [16][264]
  float* prmx = scol + 16 * 264;             // [1056]
  float* prsm = prmx + 1056;                 // [1056]
#pragma unroll
  for (int slot = 0; slot < 3; ++slot) {
    const int task = tid + slot * 512;
    if (task < ntask) {
      const int dh = task / 66, pq = task - dh * 66;
      if (pq < 66) {
        *(float4*)(scol + dh * 264 + 4 * pq) =
            {rhl[slot][0], rhl[slot][1], rhl[slot][2], rhl[slot][3]};
      }
      if (pq == 65) {
        prmx[task] = -3.4e38f; prsm[task] = 0.f;
      } else {
        const float m01 = fmaxf(rlh[slot][0], rlh[slot][1]);
        const float m23 = (pq == 64) ? rlh[slot][2] : fmaxf(rlh[slot][2], rlh[slot][3]);
        prmx[task] = fmaxf(m01, m23);
        prsm[task] = rlh[slot][0] + rlh[slot][1] + rlh[slot][2] + rlh[slot][3];
      }
    }
  }
  __syncthreads();
  float* rsM = stat;
  float* rsS = stat + (size_t)N_IMG * 264;
  float* cpM = rsS + (size_t)N_IMG * 264;
  float* cpS = cpM + (size_t)N_IMG * FSTRIP * 264;
  for (int hh = wave; hh < hcount; hh += 8) {
    float m = prmx[hh * 66 + lane], s = prsm[hh * 66 + lane];
    if (lane == 0) {
      m = fmaxf(m, fmaxf(prmx[hh * 66 + 64], prmx[hh * 66 + 65]));
      s += prsm[hh * 66 + 64] + prsm[hh * 66 + 65];
    }
#pragma unroll
    for (int off = 32; off; off >>= 1) {
      m = fmaxf(m, __shfl_xor(m, off)); s += __shfl_xor(s, off);
    }
    if (lane == 0) {
      rsM[bc * 264 + h0 + hh] = m;
      rsS[bc * 264 + h0 + hh] = s;
    }
  }
  if (tid < 264) {
    float m = -3.4e38f, s = 0.f;
    for (int dh = 0; dh < hcount; ++dh) {
      const float vv = scol[dh * 264 + tid]; m = fmaxf(m, vv); s += vv;
    }
    const size_t cb = ((size_t)bc * FSTRIP + bx) * 264 + tid;
    cpM[cb] = m; cpS[cb] = s;
  }
}

// =====================================================================
// Kernel 2: finish gates from stats only. Writes (sigmoid(y) - 1).
// =====================================================================
__global__ __launch_bounds__(256) void k_gate(
    const float* __restrict__ stat, float* __restrict__ gout,
    const float* lc1w, const float* lc1b, const float* lc2w,
    const float* lg, const float* lb, const float* lm, const float* lv,
    const float* hc1w, const float* hc1b, const float* hc2w,
    const float* hg, const float* hb, const float* hm, const float* hv) {
  __shared__ float cmx[264], csm[264], y0a[264], y0b[264];
  const int bc = blockIdx.x;
  const int tid = threadIdx.x;
  const float* rsM = stat;
  const float* rsS = stat + (size_t)N_IMG * 264;
  const float* cpM = rsS + (size_t)N_IMG * 264;
  const float* cpS = cpM + (size_t)N_IMG * FSTRIP * 264;

  for (int col = tid; col < 264; col += 256) {
    float m = -3.4e38f, s = 0.f;
    for (int st = 0; st < FSTRIP; ++st) {
      const size_t cb = ((size_t)bc * FSTRIP + st) * 264 + col;
      m = fmaxf(m, cpM[cb]); s += cpS[cb];
    }
    cmx[col] = m; csm[col] = s;
  }
  __syncthreads();
  const float lw0 = lc1w[0], lw1 = lc1w[1], lbb0 = lc1b[0];
  const float hw0 = hc1w[0], hw1 = hc1w[1], hbb0 = hc1b[0];
  for (int idx = tid; idx < NC; idx += 256) {
    y0a[idx] = lw0 * rsM[bc * 264 + idx] + lw1 * (rsS[bc * 264 + idx] * (1.f / NC)) + lbb0;
    y0b[idx] = hw0 * cmx[idx] + hw1 * (csm[idx] * (1.f / NC)) + hbb0;
  }
  __syncthreads();
  const int c = bc & (C_CH - 1);
  const float lk0 = lc2w[c * 3], lk1 = lc2w[c * 3 + 1], lk2 = lc2w[c * 3 + 2];
  const float hk0 = hc2w[c * 3], hk1 = hc2w[c * 3 + 1], hk2 = hc2w[c * 3 + 2];
  const float lsc = rsqrtf(lv[c] + 1e-5f) * lg[c], lmu = lm[c], lbe = lb[c];
  const float hsc = rsqrtf(hv[c] + 1e-5f) * hg[c], hmu = hm[c], hbe = hb[c];
  for (int idx = tid; idx < NC; idx += 256) {
    float a = idx > 0 ? y0a[idx - 1] : 0.f;
    float b = y0a[idx];
    float d = idx < NC - 1 ? y0a[idx + 1] : 0.f;
    float y = lk0 * a + lk1 * b + lk2 * d;
    y = (y - lmu) * lsc + lbe;
    gout[(size_t)bc * GPIT + idx] = 1.f / (1.f + expf(-y)) - 1.f;

    a = idx > 0 ? y0b[idx - 1] : 0.f;
    b = y0b[idx];
    d = idx < NC - 1 ? y0b[idx + 1] : 0.f;
    y = hk0 * a + hk1 * b + hk2 * d;
    y = (y - hmu) * hsc + hbe;
    gout[(size_t)N_IMG * GPIT + (size_t)bc * GPIT + idx] = 1.f / (1.f + expf(-y)) - 1.f;
  }
}

// =====================================================================
// Kernel 3: out = 2x + IDWT(0,(g-1)LH,(g'-1)HL,0). 16-row strips,
// packed-fp16 staging + column IDWT, fdot2 row IDWT, NT x/out.
// =====================================================================
__global__ __launch_bounds__(512) void k_inv(const h16* __restrict__ wsh,
                                             const float* __restrict__ gbuf,
                                             const float* __restrict__ x,
                                             float* __restrict__ out) {
  __shared__ h16 sBC[11 * PITP];   // 11,616 B: 11 rows of gated pairs
  __shared__ h16 ad2[16 * PITP];   // 16,896 B: (a, g'.d) pairs
  __shared__ h16 sghl16[264];
  // bijective XCD swizzle: nwg = 16384 = 8 * 2048
  const int p = blockIdx.x;
  const int w = (p & 7) * 2048 + (p >> 3);
  const int bc = w >> 5;               // 32 strips of 16 output rows
  const int t0 = (w & 31) * 16;
  const int u0 = t0 >> 1;              // subband rows u0..u0+10 (<=258)
  const int tid = threadIdx.x;
  const h16* sub = wsh + (size_t)bc * S2;
  const float* glh = gbuf + (size_t)bc * GPIT;
  const float* ghl = gbuf + (size_t)N_IMG * GPIT + (size_t)bc * GPIT;

  if (tid < 264) sghl16[tid] = (h16)ghl[tid];

  // stage 11 rows of {gl*LH, HL} pairs (pk_mul by {gl,1})
  for (int t = tid; t < 11 * 66; t += 512) {
    const int j = t / 66, pq = t - j * 66;
    const int u = u0 + j;
    const h16 glH = (h16)glh[u];
    const h16x2 cf = {glH, (h16)1.0f};
    const h16x8 pr = *(const h16x8*)(sub + (size_t)u * PITP + 8 * pq);
    h16x2 r0 = cf * (h16x2){pr[0], pr[1]};
    h16x2 r1 = cf * (h16x2){pr[2], pr[3]};
    h16x2 r2 = cf * (h16x2){pr[4], pr[5]};
    h16x2 r3 = cf * (h16x2){pr[6], pr[7]};
    h16x8 o = {r0[0], r0[1], r1[0], r1[1], r2[0], r2[1], r3[0], r3[1]};
    *(h16x8*)(sBC + j * PITP + 8 * pq) = o;
  }
  __syncthreads();

  // packed column IDWT: acc pair {a, d} = sum {rh,rl}*{glLH, HL}; then {1,ghl}
  for (int task = tid; task < 16 * 132; task += 512) {
    const int dt = task / 132, pq = task - dt * 132;
    const int par = dt & 1, lj0 = dt >> 1;
    h16x2 acc0 = {0, 0}, acc1 = {0, 0};
#pragma unroll
    for (int jj = 0; jj < 4; ++jj) {
      const int lj = lj0 + 3 - jj;
      const h16x2 cf = {(h16)(par ? RHI[1 + 2 * jj] : RHI[2 * jj]),
                        (h16)(par ? RLO[1 + 2 * jj] : RLO[2 * jj])};
      const h16x4 pr = *(const h16x4*)(sBC + lj * PITP + 4 * pq);
      acc0 += cf * (h16x2){pr[0], pr[1]};
      acc1 += cf * (h16x2){pr[2], pr[3]};
    }
    const h16x2 g2 = *(const h16x2*)(sghl16 + 2 * pq);
    const h16x2 cg0 = {(h16)1.0f, g2[0]};
    const h16x2 cg1 = {(h16)1.0f, g2[1]};
    acc0 *= cg0; acc1 *= cg1;
    h16x4 o = {acc0[0], acc0[1], acc1[0], acc1[1]};
    *(h16x4*)(ad2 + dt * PITP + 4 * pq) = o;
  }
  __syncthreads();

  // row IDWT via fdot2 + out = 2x + corr (nontemporal x/out)
  for (int task = tid; task < 16 * 128; task += 512) {
    const int dt = task >> 7, r = task & 127;
    const h16* row = ad2 + dt * PITP + 4 * r;       // pair q=2r at h16 idx 4r
    const h16x4 w0 = *(const h16x4*)(row);
    const h16x4 w1 = *(const h16x4*)(row + 4);
    const h16x2 w2 = *(const h16x2*)(row + 8);
    const h16x2 P[5] = {{w0[0], w0[1]}, {w0[2], w0[3]},
                        {w1[0], w1[1]}, {w1[2], w1[3]}, w2};
    float vv[4];
#pragma unroll
    for (int k = 0; k < 4; ++k) {
      const int base = k >> 1, par = k & 1;
      float s = 0.f;
#pragma unroll
      for (int jj = 0; jj < 4; ++jj) {
        const h16x2 cf = {(h16)RLO[par + 2 * jj], (h16)RHI[par + 2 * jj]};
        s = FDOT2(P[base + 3 - jj], cf, s);
      }
      vv[k] = s;
    }
    const size_t orow = ((size_t)bc * H_IN + (size_t)(t0 + dt)) * W_IN + 4 * r;
    const f32x4 xv = __builtin_nontemporal_load((const f32x4*)(x + orow));
    f32x4 ov;
    ov.x = 2.f * xv.x + vv[0]; ov.y = 2.f * xv.y + vv[1];
    ov.z = 2.f * xv.z + vv[2]; ov.w = 2.f * xv.w + vv[3];
    __builtin_nontemporal_store(ov, (f32x4*)(out + orow));
  }
}

extern "C" void kernel_launch(void* const* d_in, const int* in_sizes, int n_in,
                              void* d_out, int out_size, void* d_ws, size_t ws_size,
                              hipStream_t stream) {
  const float* x = (const float*)d_in[0];
  h16* wsh = (h16*)d_ws;
  float* statf = (float*)(wsh + (size_t)N_IMG * S2);
  // stat layout: rsM[512*264] | rsS | cpM[512*17*264] | cpS | glh | ghl
  float* gbuf = statf + 2 * (size_t)N_IMG * 264 + 2 * (size_t)N_IMG * FSTRIP * 264;
  float* out = (float*)d_out;

  k_fwd<<<dim3(FSTRIP * N_IMG), 512, 0, stream>>>(x, wsh, statf);
  k_gate<<<dim3(N_IMG), 256, 0, stream>>>(
      statf, gbuf,
      (const float*)d_in[1], (const float*)d_in[2], (const float*)d_in[3],
      (const float*)d_in[4], (const float*)d_in[5], (const float*)d_in[6], (const float*)d_in[7],
      (const float*)d_in[8], (const float*)d_in[9], (const float*)d_in[10],
      (const float*)d_in[11], (const float*)d_in[12], (const float*)d_in[13], (const float*)d_in[14]);
  k_inv<<<dim3(32 * N_IMG), 512, 0, stream>>>(wsh, gbuf, x, out);
}